// Round 4
// baseline (925.033 us; speedup 1.0000x reference)
//
#include <hip/hip_runtime.h>

// ---------------- conv1 (3x3, 1->32, SAME) + relu + maxpool2 ----------------
// in : (32,128,128,1)  out: pool1 (32,64,64,32) NHWC flat
__global__ void k_conv1_pool(const float* __restrict__ x, const float* __restrict__ w,
                             const float* __restrict__ bias, float* __restrict__ out) {
    int t = blockIdx.x * blockDim.x + threadIdx.x;   // 32*64*64*32 = 4194304
    int c  = t & 31;
    int pw = (t >> 5) & 63;
    int ph = (t >> 11) & 63;
    int n  = t >> 17;
    float wv[9];
#pragma unroll
    for (int i = 0; i < 9; ++i) wv[i] = w[i * 32 + c];
    float b = bias[c];
    float patch[4][4];
#pragma unroll
    for (int r = 0; r < 4; ++r) {
        int gr = 2 * ph - 1 + r;
#pragma unroll
        for (int col = 0; col < 4; ++col) {
            int gc = 2 * pw - 1 + col;
            patch[r][col] = (gr >= 0 && gr < 128 && gc >= 0 && gc < 128)
                ? x[(n * 128 + gr) * 128 + gc] : 0.f;
        }
    }
    float m = 0.f;  // relu >= 0, so max-with-0 == pool(relu)
#pragma unroll
    for (int dh = 0; dh < 2; ++dh)
#pragma unroll
    for (int dw = 0; dw < 2; ++dw) {
        float s = b;
#pragma unroll
        for (int kh = 0; kh < 3; ++kh)
#pragma unroll
        for (int kw = 0; kw < 3; ++kw)
            s = fmaf(patch[dh + kh][dw + kw], wv[kh * 3 + kw], s);
        m = fmaxf(m, s);
    }
    out[t] = m;   // t == ((n*64+ph)*64+pw)*32+c
}

// ---------------- transpose conv2 weights: (kh,kw,ci,co) -> (kh,kw,co,ci) ----
// R1-proven version. DO NOT TOUCH without a verified conv2 to match.
__global__ void k_w2t(const float* __restrict__ w2, float* __restrict__ w2t) {
    int t = blockIdx.x * blockDim.x + threadIdx.x;   // 9*64*32 = 18432
    if (t >= 18432) return;
    int ci = t & 31;
    int co = (t >> 5) & 63;
    int p  = t >> 11;                 // kh*3+kw
    w2t[t] = w2[(p * 32 + ci) * 64 + co];
}

// ---------------- conv2 (3x3, 32->64, SAME) + relu ---------------------------
// R1-proven version (the R2 restructure broke correctness; reverted verbatim).
__global__ void k_conv2(const float* __restrict__ in, const float* __restrict__ w2t,
                        const float* __restrict__ bias, float* __restrict__ out) {
    __shared__ float lds[10 * 10 * 32];   // 12.8 KB, [row][col][ci]
    int bid = blockIdx.x;                 // 32 n * 64 tiles = 2048
    int n = bid >> 6;
    int tile = bid & 63;
    int r0b = (tile >> 3) * 8;
    int c0b = (tile & 7) * 8;
    int tid = threadIdx.x;
    for (int i = tid; i < 3200; i += 256) {
        int ci = i & 31;
        int cr = i >> 5;
        int col = cr % 10;
        int row = cr / 10;
        int gr = r0b - 1 + row;
        int gc = c0b - 1 + col;
        float v = 0.f;
        if (gr >= 0 && gr < 64 && gc >= 0 && gc < 64)
            v = in[((n * 64 + gr) * 64 + gc) * 32 + ci];
        lds[i] = v;
    }
    __syncthreads();
    int co = tid & 63;
    int rp = tid >> 6;                    // 0..3 -> out rows rp*2, rp*2+1
    float bb = bias[co];
    float acc[2][8];
#pragma unroll
    for (int r = 0; r < 2; ++r)
#pragma unroll
        for (int c = 0; c < 8; ++c) acc[r][c] = bb;

#pragma unroll
    for (int q = 0; q < 4; ++q) {         // lds row rp*2+q
        int ldsrow = rp * 2 + q;
        for (int ci4 = 0; ci4 < 8; ++ci4) {
            float4 v[10];
#pragma unroll
            for (int j = 0; j < 10; ++j)
                v[j] = *(const float4*)&lds[ldsrow * 320 + j * 32 + ci4 * 4];
#pragma unroll
            for (int r = 0; r < 2; ++r) {
                int kh = q - r;
                if (kh < 0 || kh > 2) continue;
#pragma unroll
                for (int kw = 0; kw < 3; ++kw) {
                    float4 wv = *(const float4*)&w2t[((kh * 3 + kw) * 64 + co) * 32 + ci4 * 4];
#pragma unroll
                    for (int c = 0; c < 8; ++c) {
                        float4 xv = v[c + kw];
                        float a = acc[r][c];
                        a = fmaf(xv.x, wv.x, a);
                        a = fmaf(xv.y, wv.y, a);
                        a = fmaf(xv.z, wv.z, a);
                        a = fmaf(xv.w, wv.w, a);
                        acc[r][c] = a;
                    }
                }
            }
        }
    }
#pragma unroll
    for (int r = 0; r < 2; ++r) {
        int gr = r0b + rp * 2 + r;
#pragma unroll
        for (int c = 0; c < 8; ++c) {
            int gc = c0b + c;
            out[((n * 64 + gr) * 64 + gc) * 64 + co] = fmaxf(acc[r][c], 0.f);
        }
    }
}

// ---------------- argmax phase A: per (n, part of 256 pos) -------------------
__global__ void k_argmax_A(const float* __restrict__ conv2, float* __restrict__ abest,
                           int* __restrict__ aidx, float* __restrict__ asum) {
    int n = blockIdx.x, part = blockIdx.y;
    int tid = threadIdx.x;
    int c = tid & 63, sub = tid >> 6;
    const float* base = conv2 + (size_t)n * 4096 * 64;
    int p0 = part * 256 + sub * 64;
    float best = -1e30f; int bi = p0; float s = 0.f;
    for (int i = 0; i < 64; ++i) {
        int p = p0 + i;
        float v = base[(size_t)p * 64 + c];
        s += v;
        if (v > best) { best = v; bi = p; }
    }
    __shared__ float sb[256], ss[256];
    __shared__ int sidx[256];
    sb[tid] = best; ss[tid] = s; sidx[tid] = bi;
    __syncthreads();
    if (sub == 0) {
        for (int pp = 1; pp < 4; ++pp) {      // ascending order -> first-occurrence
            float v = sb[pp * 64 + c];
            if (v > best) { best = v; bi = sidx[pp * 64 + c]; }
            s += ss[pp * 64 + c];
        }
        int o = (n * 16 + part) * 64 + c;
        abest[o] = best; aidx[o] = bi; asum[o] = s;
    }
}

// ---------------- argmax phase B: combine 16 parts in order ------------------
__global__ void k_argmax_B(const float* __restrict__ abest, const int* __restrict__ aidx,
                           const float* __restrict__ asum, int* __restrict__ idx,
                           float* __restrict__ psum) {
    int n = blockIdx.x;                   // 32
    int c = threadIdx.x;                  // 64
    float best = -1e30f; int bi = 0; float s = 0.f;
    for (int part = 0; part < 16; ++part) {
        int o = (n * 16 + part) * 64 + c;
        float v = abest[o];
        s += asum[o];
        if (v > best) { best = v; bi = aidx[o]; }
    }
    idx[n * 64 + c] = bi;
    psum[n * 64 + c] = s;
}

// ---------------- mask * conv2, relu, maxpool2 -> conv2_pool (32,32,32,64) ---
__global__ void k_mask_pool(const float* __restrict__ conv2, const int* __restrict__ idx,
                            float* __restrict__ out) {
    int t = blockIdx.x * blockDim.x + threadIdx.x;   // 2097152
    int c  = t & 63;
    int pw = (t >> 6) & 31;
    int ph = (t >> 11) & 31;
    int n  = t >> 16;
    int id = idx[n * 64 + c];
    float ih = (float)(id >> 6);
    float iw = (float)(id & 63);
    float m = 0.f;
#pragma unroll
    for (int dh = 0; dh < 2; ++dh) {
#pragma unroll
        for (int dw = 0; dw < 2; ++dw) {
            int h = 2 * ph + dh, w = 2 * pw + dw;
            float d = (fabsf((float)h - ih) + fabsf((float)w - iw)) * (1.0f / 31.5f);
            float mask = fmaxf(1.0f - 0.5f * d, -1.0f);
            float v = conv2[(((size_t)n * 64 + h) * 64 + w) * 64 + c] * mask;
            m = fmaxf(m, v);
        }
    }
    out[t] = m;
}

// ---------------- dense1 split-K GEMM: (32,65536)@(65536,1024) ---------------
// grid (256 K-chunks of 256, 2 j-halves); block 256. NO weight re-read across
// blocks (j-split, not n-split): total weight fetch = 268 MB exactly.
// Thread: 2 consecutive j (float2 weight loads), 32 n accumulators.
__global__ void k_dense1_partial(const float* __restrict__ xflat,
                                 const float* __restrict__ w1,
                                 float* __restrict__ partial) {
    __shared__ float xs[32 * 256];        // 32 KB, [n][k]
    int chunk = blockIdx.x;               // 0..255
    int jg = blockIdx.y;                  // 0..1
    int tid = threadIdx.x;
    int k0 = chunk * 256;
    // stage activations once (float4, coalesced): 2048 float4
    for (int i = tid; i < 2048; i += 256) {
        int n = i >> 6, kq = i & 63;
        *(float4*)&xs[n * 256 + kq * 4] =
            *(const float4*)&xflat[(size_t)n * 65536 + k0 + kq * 4];
    }
    __syncthreads();
    int j0 = jg * 512 + tid * 2;          // wave covers 512 B contiguous
    float2 acc[32];
#pragma unroll
    for (int n = 0; n < 32; ++n) acc[n] = float2{0.f, 0.f};
    for (int k4 = 0; k4 < 64; ++k4) {
        int k = k4 * 4;
        float2 w[4];
#pragma unroll
        for (int i = 0; i < 4; ++i)
            w[i] = *(const float2*)&w1[(size_t)(k0 + k + i) * 1024 + j0];
#pragma unroll
        for (int n = 0; n < 32; ++n) {
            float4 xv = *(const float4*)&xs[n * 256 + k];   // broadcast, conflict-free
            float2 a = acc[n];
            a.x = fmaf(xv.x, w[0].x, a.x);  a.y = fmaf(xv.x, w[0].y, a.y);
            a.x = fmaf(xv.y, w[1].x, a.x);  a.y = fmaf(xv.y, w[1].y, a.y);
            a.x = fmaf(xv.z, w[2].x, a.x);  a.y = fmaf(xv.z, w[2].y, a.y);
            a.x = fmaf(xv.w, w[3].x, a.x);  a.y = fmaf(xv.w, w[3].y, a.y);
            acc[n] = a;
        }
    }
#pragma unroll
    for (int n = 0; n < 32; ++n)
        *(float2*)&partial[((size_t)chunk * 32 + n) * 1024 + j0] = acc[n];
}

// ---------------- reduce partials + bias + relu -> dense_out (32,1024) -------
__global__ void k_dense1_reduce(const float* __restrict__ partial, const float* __restrict__ b,
                                float* __restrict__ dout) {
    int t = blockIdx.x * blockDim.x + threadIdx.x;   // 32768
    int n = t >> 10, j = t & 1023;
    float s = b[j];
    for (int ch = 0; ch < 256; ++ch)
        s += partial[((size_t)ch * 32 + n) * 1024 + j];
    dout[t] = fmaxf(s, 0.f);
}

// ---------------- dense2 -> logits (32,10) -----------------------------------
__global__ void k_dense2(const float* __restrict__ dout, const float* __restrict__ w,
                         const float* __restrict__ b, float* __restrict__ logits) {
    int bid = blockIdx.x;                 // 320 = 32 n * 10 j
    int n = bid / 10, j = bid % 10;
    int lane = threadIdx.x;               // 64
    float s = 0.f;
    for (int k = lane; k < 1024; k += 64)
        s = fmaf(dout[n * 1024 + k], w[k * 10 + j], s);
#pragma unroll
    for (int off = 32; off > 0; off >>= 1)
        s += __shfl_down(s, off);
    if (lane == 0) logits[n * 10 + j] = s + b[j];
}

// ---------------- per-category avg + argmax (np NaN-first semantics) ---------
__global__ void k_filter_cat(const float* __restrict__ psum, const int* __restrict__ labels,
                             float* __restrict__ out) {
    int c = threadIdx.x;                  // 64
    float sums[10]; int cnt[10];
#pragma unroll
    for (int i = 0; i < 10; ++i) { sums[i] = 0.f; cnt[i] = 0; }
    for (int bb = 0; bb < 32; ++bb) {
        int l = labels[bb];
        sums[l] += psum[bb * 64 + c];
        cnt[l]++;
    }
    int best_i = 0; float best = -1e30f;
    for (int i = 0; i < 10; ++i) {
        float v = sums[i] / (float)cnt[i];   // 0/0 -> NaN when category empty
        if (v != v) { best_i = i; break; }   // np.argmax: first NaN wins
        if (v > best) { best = v; best_i = i; }
    }
    out[c] = (float)best_i;
}

extern "C" void kernel_launch(void* const* d_in, const int* in_sizes, int n_in,
                              void* d_out, int out_size, void* d_ws, size_t ws_size,
                              hipStream_t stream) {
    const float* x    = (const float*)d_in[0];
    const int* labels = (const int*)d_in[1];
    const float* c1w  = (const float*)d_in[2];
    const float* c1b  = (const float*)d_in[3];
    const float* c2w  = (const float*)d_in[4];
    const float* c2b  = (const float*)d_in[5];
    const float* d1w  = (const float*)d_in[6];
    const float* d1b  = (const float*)d_in[7];
    const float* d2w  = (const float*)d_in[8];
    const float* d2b  = (const float*)d_in[9];
    float* out = (float*)d_out;
    float* ws  = (float*)d_ws;

    // workspace layout (floats).
    // partial (256*32*1024 = 8,388,608) ALIASES conv2o (dead after k_mask_pool).
    float* pool1   = ws;                       // 4,194,304  (32,64,64,32)
    float* conv2o  = ws + 4194304;             // 8,388,608  (32,64,64,64)
    float* partial = conv2o;                   // 8,388,608  (256,32,1024) - alias
    float* w2t     = ws + 12582912;            // 18,432
    int*   idx     = (int*)(ws + 12601344);    // 2,048
    float* psum    = ws + 12603392;            // 2,048
    float* abest   = ws + 12605440;            // 32,768 (32,16,64)
    int*   aidx    = (int*)(ws + 12638208);    // 32,768
    float* asum    = ws + 12670976;            // 32,768
    float* dense1o = ws + 12703744;            // 32,768 (32,1024)

    float* logits = out;                       // 320
    float* pool2  = out + 320;                 // 2,097,152  (32,32,32,64)
    float* fcat   = out + 320 + 2097152;       // 64

    k_w2t<<<72, 256, 0, stream>>>(c2w, w2t);
    k_conv1_pool<<<16384, 256, 0, stream>>>(x, c1w, c1b, pool1);
    k_conv2<<<2048, 256, 0, stream>>>(pool1, w2t, c2b, conv2o);
    dim3 ga(32, 16);
    k_argmax_A<<<ga, 256, 0, stream>>>(conv2o, abest, aidx, asum);
    k_argmax_B<<<32, 64, 0, stream>>>(abest, aidx, asum, idx, psum);
    k_mask_pool<<<8192, 256, 0, stream>>>(conv2o, idx, pool2);
    dim3 g5(256, 2);
    k_dense1_partial<<<g5, 256, 0, stream>>>(pool2, d1w, partial);
    k_dense1_reduce<<<128, 256, 0, stream>>>(partial, d1b, dense1o);
    k_dense2<<<320, 64, 0, stream>>>(dense1o, d2w, d2b, logits);
    k_filter_cat<<<1, 64, 0, stream>>>(psum, labels, fcat);
}

// Round 5
// 688.788 us; speedup vs baseline: 1.3430x; 1.3430x over previous
//
#include <hip/hip_runtime.h>

// ---------------- conv1 (3x3, 1->32, SAME) + relu + maxpool2 ----------------
// in : (32,128,128,1)  out: pool1 (32,64,64,32) NHWC flat
__global__ void k_conv1_pool(const float* __restrict__ x, const float* __restrict__ w,
                             const float* __restrict__ bias, float* __restrict__ out) {
    int t = blockIdx.x * blockDim.x + threadIdx.x;   // 32*64*64*32 = 4194304
    int c  = t & 31;
    int pw = (t >> 5) & 63;
    int ph = (t >> 11) & 63;
    int n  = t >> 17;
    float wv[9];
#pragma unroll
    for (int i = 0; i < 9; ++i) wv[i] = w[i * 32 + c];
    float b = bias[c];
    float patch[4][4];
#pragma unroll
    for (int r = 0; r < 4; ++r) {
        int gr = 2 * ph - 1 + r;
#pragma unroll
        for (int col = 0; col < 4; ++col) {
            int gc = 2 * pw - 1 + col;
            patch[r][col] = (gr >= 0 && gr < 128 && gc >= 0 && gc < 128)
                ? x[(n * 128 + gr) * 128 + gc] : 0.f;
        }
    }
    float m = 0.f;  // relu >= 0, so max-with-0 == pool(relu)
#pragma unroll
    for (int dh = 0; dh < 2; ++dh)
#pragma unroll
    for (int dw = 0; dw < 2; ++dw) {
        float s = b;
#pragma unroll
        for (int kh = 0; kh < 3; ++kh)
#pragma unroll
        for (int kw = 0; kw < 3; ++kw)
            s = fmaf(patch[dh + kh][dw + kw], wv[kh * 3 + kw], s);
        m = fmaxf(m, s);
    }
    out[t] = m;   // t == ((n*64+ph)*64+pw)*32+c
}

// ---------------- transpose conv2 weights: (kh,kw,ci,co) -> (kh,kw,co,ci) ----
// R1-proven version. DO NOT TOUCH without a verified conv2 to match.
__global__ void k_w2t(const float* __restrict__ w2, float* __restrict__ w2t) {
    int t = blockIdx.x * blockDim.x + threadIdx.x;   // 9*64*32 = 18432
    if (t >= 18432) return;
    int ci = t & 31;
    int co = (t >> 5) & 63;
    int p  = t >> 11;                 // kh*3+kw
    w2t[t] = w2[(p * 32 + ci) * 64 + co];
}

// ---------------- conv2 (3x3, 32->64, SAME) + relu ---------------------------
// FMA ORDER FROZEN (R2 post-mortem: reassociation flips argmax near-ties).
// Only change vs R1: weight float4 loads hoisted to top of each (q,ci4) body —
// identical values & FMA sequence, loads issued together for latency overlap.
__global__ void k_conv2(const float* __restrict__ in, const float* __restrict__ w2t,
                        const float* __restrict__ bias, float* __restrict__ out) {
    __shared__ float lds[10 * 10 * 32];   // 12.8 KB, [row][col][ci]
    int bid = blockIdx.x;                 // 32 n * 64 tiles = 2048
    int n = bid >> 6;
    int tile = bid & 63;
    int r0b = (tile >> 3) * 8;
    int c0b = (tile & 7) * 8;
    int tid = threadIdx.x;
    for (int i = tid; i < 3200; i += 256) {
        int ci = i & 31;
        int cr = i >> 5;
        int col = cr % 10;
        int row = cr / 10;
        int gr = r0b - 1 + row;
        int gc = c0b - 1 + col;
        float v = 0.f;
        if (gr >= 0 && gr < 64 && gc >= 0 && gc < 64)
            v = in[((n * 64 + gr) * 64 + gc) * 32 + ci];
        lds[i] = v;
    }
    __syncthreads();
    int co = tid & 63;
    int rp = tid >> 6;                    // 0..3 -> out rows rp*2, rp*2+1
    float bb = bias[co];
    float acc[2][8];
#pragma unroll
    for (int r = 0; r < 2; ++r)
#pragma unroll
        for (int c = 0; c < 8; ++c) acc[r][c] = bb;

#pragma unroll
    for (int q = 0; q < 4; ++q) {         // lds row rp*2+q
        int ldsrow = rp * 2 + q;
        for (int ci4 = 0; ci4 < 8; ++ci4) {
            // hoisted weight loads: r=0 uses kh=q (valid q<=2), r=1 uses kh=q-1 (q>=1)
            float4 wA[3], wB[3];
            if (q <= 2) {
#pragma unroll
                for (int kw = 0; kw < 3; ++kw)
                    wA[kw] = *(const float4*)&w2t[((q * 3 + kw) * 64 + co) * 32 + ci4 * 4];
            }
            if (q >= 1) {
#pragma unroll
                for (int kw = 0; kw < 3; ++kw)
                    wB[kw] = *(const float4*)&w2t[(((q - 1) * 3 + kw) * 64 + co) * 32 + ci4 * 4];
            }
            float4 v[10];
#pragma unroll
            for (int j = 0; j < 10; ++j)
                v[j] = *(const float4*)&lds[ldsrow * 320 + j * 32 + ci4 * 4];
            // r = 0 (kh = q)
            if (q <= 2) {
#pragma unroll
                for (int kw = 0; kw < 3; ++kw) {
                    float4 wv = wA[kw];
#pragma unroll
                    for (int c = 0; c < 8; ++c) {
                        float4 xv = v[c + kw];
                        float a = acc[0][c];
                        a = fmaf(xv.x, wv.x, a);
                        a = fmaf(xv.y, wv.y, a);
                        a = fmaf(xv.z, wv.z, a);
                        a = fmaf(xv.w, wv.w, a);
                        acc[0][c] = a;
                    }
                }
            }
            // r = 1 (kh = q-1)
            if (q >= 1) {
#pragma unroll
                for (int kw = 0; kw < 3; ++kw) {
                    float4 wv = wB[kw];
#pragma unroll
                    for (int c = 0; c < 8; ++c) {
                        float4 xv = v[c + kw];
                        float a = acc[1][c];
                        a = fmaf(xv.x, wv.x, a);
                        a = fmaf(xv.y, wv.y, a);
                        a = fmaf(xv.z, wv.z, a);
                        a = fmaf(xv.w, wv.w, a);
                        acc[1][c] = a;
                    }
                }
            }
        }
    }
#pragma unroll
    for (int r = 0; r < 2; ++r) {
        int gr = r0b + rp * 2 + r;
#pragma unroll
        for (int c = 0; c < 8; ++c) {
            int gc = c0b + c;
            out[((n * 64 + gr) * 64 + gc) * 64 + co] = fmaxf(acc[r][c], 0.f);
        }
    }
}

// ---------------- argmax phase A: per (n, part of 256 pos) -------------------
__global__ void k_argmax_A(const float* __restrict__ conv2, float* __restrict__ abest,
                           int* __restrict__ aidx, float* __restrict__ asum) {
    int n = blockIdx.x, part = blockIdx.y;
    int tid = threadIdx.x;
    int c = tid & 63, sub = tid >> 6;
    const float* base = conv2 + (size_t)n * 4096 * 64;
    int p0 = part * 256 + sub * 64;
    float best = -1e30f; int bi = p0; float s = 0.f;
    for (int i = 0; i < 64; ++i) {
        int p = p0 + i;
        float v = base[(size_t)p * 64 + c];
        s += v;
        if (v > best) { best = v; bi = p; }
    }
    __shared__ float sb[256], ss[256];
    __shared__ int sidx[256];
    sb[tid] = best; ss[tid] = s; sidx[tid] = bi;
    __syncthreads();
    if (sub == 0) {
        for (int pp = 1; pp < 4; ++pp) {      // ascending order -> first-occurrence
            float v = sb[pp * 64 + c];
            if (v > best) { best = v; bi = sidx[pp * 64 + c]; }
            s += ss[pp * 64 + c];
        }
        int o = (n * 16 + part) * 64 + c;
        abest[o] = best; aidx[o] = bi; asum[o] = s;
    }
}

// ---------------- argmax phase B: combine 16 parts in order ------------------
__global__ void k_argmax_B(const float* __restrict__ abest, const int* __restrict__ aidx,
                           const float* __restrict__ asum, int* __restrict__ idx,
                           float* __restrict__ psum) {
    int n = blockIdx.x;                   // 32
    int c = threadIdx.x;                  // 64
    float best = -1e30f; int bi = 0; float s = 0.f;
    for (int part = 0; part < 16; ++part) {
        int o = (n * 16 + part) * 64 + c;
        float v = abest[o];
        s += asum[o];
        if (v > best) { best = v; bi = aidx[o]; }
    }
    idx[n * 64 + c] = bi;
    psum[n * 64 + c] = s;
}

// ---------------- mask * conv2, relu, maxpool2 -> conv2_pool (32,32,32,64) ---
__global__ void k_mask_pool(const float* __restrict__ conv2, const int* __restrict__ idx,
                            float* __restrict__ out) {
    int t = blockIdx.x * blockDim.x + threadIdx.x;   // 2097152
    int c  = t & 63;
    int pw = (t >> 6) & 31;
    int ph = (t >> 11) & 31;
    int n  = t >> 16;
    int id = idx[n * 64 + c];
    float ih = (float)(id >> 6);
    float iw = (float)(id & 63);
    float m = 0.f;
#pragma unroll
    for (int dh = 0; dh < 2; ++dh) {
#pragma unroll
        for (int dw = 0; dw < 2; ++dw) {
            int h = 2 * ph + dh, w = 2 * pw + dw;
            float d = (fabsf((float)h - ih) + fabsf((float)w - iw)) * (1.0f / 31.5f);
            float mask = fmaxf(1.0f - 0.5f * d, -1.0f);
            float v = conv2[(((size_t)n * 64 + h) * 64 + w) * 64 + c] * mask;
            m = fmaxf(m, v);
        }
    }
    out[t] = m;
}

// ---------------- dense1 split-K GEMM: (32,65536)@(65536,1024) ---------------
// grid (256 K-chunks of 256, 4 j-groups of 256); block 256 -> 1024 blocks
// (4/CU, 16 waves/CU). j-split: zero weight re-read (268 MB total).
// 1 j per thread, 32 n accumulators, distance-1 weight prefetch pipeline.
__global__ void k_dense1_partial(const float* __restrict__ xflat,
                                 const float* __restrict__ w1,
                                 float* __restrict__ partial) {
    __shared__ float xs[32 * 256];        // 32 KB, [n][k]
    int chunk = blockIdx.x;               // 0..255
    int jg = blockIdx.y;                  // 0..3
    int tid = threadIdx.x;
    int k0 = chunk * 256;
    for (int i = tid; i < 2048; i += 256) {
        int n = i >> 6, kq = i & 63;
        *(float4*)&xs[n * 256 + kq * 4] =
            *(const float4*)&xflat[(size_t)n * 65536 + k0 + kq * 4];
    }
    __syncthreads();
    int j = jg * 256 + tid;               // wave covers 256 B contiguous
    float acc[32];
#pragma unroll
    for (int n = 0; n < 32; ++n) acc[n] = 0.f;
    const float* wp = w1 + (size_t)k0 * 1024 + j;
    float w[4], wn[4];
#pragma unroll
    for (int i = 0; i < 4; ++i) w[i] = wp[(size_t)i * 1024];
    for (int k4 = 0; k4 < 64; ++k4) {
        int k = k4 * 4;
        int kpre = (k4 < 63) ? (k + 4) : 0;   // safe dummy on last iter
#pragma unroll
        for (int i = 0; i < 4; ++i)
            wn[i] = wp[(size_t)(kpre + i) * 1024];
#pragma unroll
        for (int n = 0; n < 32; ++n) {
            float4 xv = *(const float4*)&xs[n * 256 + k];   // broadcast, conflict-free
            float a = acc[n];
            a = fmaf(xv.x, w[0], a);
            a = fmaf(xv.y, w[1], a);
            a = fmaf(xv.z, w[2], a);
            a = fmaf(xv.w, w[3], a);
            acc[n] = a;
        }
#pragma unroll
        for (int i = 0; i < 4; ++i) w[i] = wn[i];
    }
#pragma unroll
    for (int n = 0; n < 32; ++n)
        partial[((size_t)chunk * 32 + n) * 1024 + j] = acc[n];
}

// ---------------- reduce partials + bias + relu -> dense_out (32,1024) -------
__global__ void k_dense1_reduce(const float* __restrict__ partial, const float* __restrict__ b,
                                float* __restrict__ dout) {
    int t = blockIdx.x * blockDim.x + threadIdx.x;   // 32768
    int n = t >> 10, j = t & 1023;
    float s = b[j];
    for (int ch = 0; ch < 256; ++ch)
        s += partial[((size_t)ch * 32 + n) * 1024 + j];
    dout[t] = fmaxf(s, 0.f);
}

// ---------------- dense2 -> logits (32,10) -----------------------------------
__global__ void k_dense2(const float* __restrict__ dout, const float* __restrict__ w,
                         const float* __restrict__ b, float* __restrict__ logits) {
    int bid = blockIdx.x;                 // 320 = 32 n * 10 j
    int n = bid / 10, j = bid % 10;
    int lane = threadIdx.x;               // 64
    float s = 0.f;
    for (int k = lane; k < 1024; k += 64)
        s = fmaf(dout[n * 1024 + k], w[k * 10 + j], s);
#pragma unroll
    for (int off = 32; off > 0; off >>= 1)
        s += __shfl_down(s, off);
    if (lane == 0) logits[n * 10 + j] = s + b[j];
}

// ---------------- per-category avg + argmax (np NaN-first semantics) ---------
__global__ void k_filter_cat(const float* __restrict__ psum, const int* __restrict__ labels,
                             float* __restrict__ out) {
    int c = threadIdx.x;                  // 64
    float sums[10]; int cnt[10];
#pragma unroll
    for (int i = 0; i < 10; ++i) { sums[i] = 0.f; cnt[i] = 0; }
    for (int bb = 0; bb < 32; ++bb) {
        int l = labels[bb];
        sums[l] += psum[bb * 64 + c];
        cnt[l]++;
    }
    int best_i = 0; float best = -1e30f;
    for (int i = 0; i < 10; ++i) {
        float v = sums[i] / (float)cnt[i];   // 0/0 -> NaN when category empty
        if (v != v) { best_i = i; break; }   // np.argmax: first NaN wins
        if (v > best) { best = v; best_i = i; }
    }
    out[c] = (float)best_i;
}

extern "C" void kernel_launch(void* const* d_in, const int* in_sizes, int n_in,
                              void* d_out, int out_size, void* d_ws, size_t ws_size,
                              hipStream_t stream) {
    const float* x    = (const float*)d_in[0];
    const int* labels = (const int*)d_in[1];
    const float* c1w  = (const float*)d_in[2];
    const float* c1b  = (const float*)d_in[3];
    const float* c2w  = (const float*)d_in[4];
    const float* c2b  = (const float*)d_in[5];
    const float* d1w  = (const float*)d_in[6];
    const float* d1b  = (const float*)d_in[7];
    const float* d2w  = (const float*)d_in[8];
    const float* d2b  = (const float*)d_in[9];
    float* out = (float*)d_out;
    float* ws  = (float*)d_ws;

    // workspace layout (floats).
    // partial (256*32*1024 = 8,388,608) ALIASES conv2o (dead after k_mask_pool).
    float* pool1   = ws;                       // 4,194,304  (32,64,64,32)
    float* conv2o  = ws + 4194304;             // 8,388,608  (32,64,64,64)
    float* partial = conv2o;                   // 8,388,608  (256,32,1024) - alias
    float* w2t     = ws + 12582912;            // 18,432
    int*   idx     = (int*)(ws + 12601344);    // 2,048
    float* psum    = ws + 12603392;            // 2,048
    float* abest   = ws + 12605440;            // 32,768 (32,16,64)
    int*   aidx    = (int*)(ws + 12638208);    // 32,768
    float* asum    = ws + 12670976;            // 32,768
    float* dense1o = ws + 12703744;            // 32,768 (32,1024)

    float* logits = out;                       // 320
    float* pool2  = out + 320;                 // 2,097,152  (32,32,32,64)
    float* fcat   = out + 320 + 2097152;       // 64

    k_w2t<<<72, 256, 0, stream>>>(c2w, w2t);
    k_conv1_pool<<<16384, 256, 0, stream>>>(x, c1w, c1b, pool1);
    k_conv2<<<2048, 256, 0, stream>>>(pool1, w2t, c2b, conv2o);
    dim3 ga(32, 16);
    k_argmax_A<<<ga, 256, 0, stream>>>(conv2o, abest, aidx, asum);
    k_argmax_B<<<32, 64, 0, stream>>>(abest, aidx, asum, idx, psum);
    k_mask_pool<<<8192, 256, 0, stream>>>(conv2o, idx, pool2);
    dim3 g5(256, 4);
    k_dense1_partial<<<g5, 256, 0, stream>>>(pool2, d1w, partial);
    k_dense1_reduce<<<128, 256, 0, stream>>>(partial, d1b, dense1o);
    k_dense2<<<320, 64, 0, stream>>>(dense1o, d2w, d2b, logits);
    k_filter_cat<<<1, 64, 0, stream>>>(psum, labels, fcat);
}